// Round 8
// baseline (5971.540 us; speedup 1.0000x reference)
//
#include <hip/hip_runtime.h>
#include <math.h>

// Problem constants
#define S_    32
#define U_    10
#define B_    320           // S*U sequences
#define T_    120
#define NMEL_ 40
#define H_    768
#define G4_   3072          // 4*H gates
#define D_    256
#define XP_   64            // mel features zero-padded 40 -> 64
#define K0_   (XP_ + H_)    // 832, layer-0 fused K
#define K12_  (2 * H_)      // 1536, layers 1/2 fused K
#define NP_   4             // h-buffer parities

#define NB_   48            // blocks per layer (16 units each, all layers)
#define NBLK  (3 * NB_)     // 144 blocks

// LDS: W chunk-major 64B rows XOR-swizzled + A-stage ring.
// layers 1/2: 24 chunks * 64 * 64 = 98,304 + 3 * 20,480 ring = 159,744
// layer 0:    26 chunks * 64 * 64 = 106,496 + 2 * 20,480 ring = 147,456
#define SMEM_BYTES 159744
#define WLDS12 24           // W chunks resident in LDS for layers 1/2 (rest streamed)

typedef _Float16 half8 __attribute__((ext_vector_type(8)));
typedef float floatx4 __attribute__((ext_vector_type(4)));

__device__ __forceinline__ float sigm(float x) {
  return 1.f / (1.f + __expf(-x));
}
__device__ __forceinline__ float tanh_f(float x) {
  x = fminf(15.f, fmaxf(-15.f, x));
  float e = __expf(2.f * x);
  return (e - 1.f) / (e + 1.f);
}

// async global->LDS DMA, 16 B per lane; LDS dest = wave-uniform base + lane*16.
// AUX = cpol: 17 = sc0|sc1 -> bypass CU L1 AND XCD L2 (read at coherence
// point). R7-verified: h freshness with NO invalidate machinery.
// AUX = 0: normal caching (constant data: x0, streamed W tiles stay L2-hot).
template <int AUX>
__device__ __forceinline__ void dma16(const void* g, void* l) {
  __builtin_amdgcn_global_load_lds(
      (const __attribute__((address_space(1))) unsigned int*)g,
      (__attribute__((address_space(3))) unsigned int*)l, 16, 0, AUX);
}

// s_waitcnt vmcnt(N) only (expcnt/lgkmcnt all-ones = no wait)
template <int N>
__device__ __forceinline__ void waitvm() {
  __builtin_amdgcn_s_waitcnt(0x3FF0 | (N & 0xF) | ((N >> 4) << 14));
}

// inline-asm 16B global load to VGPR (issue order pinned; counted by hand).
// Normal caching: W tiles are constant -> L2-resident.
__device__ __forceinline__ half8 aload(const _Float16* p) {
  half8 d;
  asm volatile("global_load_dwordx4 %0, %1, off" : "=v"(d) : "v"(p));
  return d;
}

// ---------------- prep kernels ----------------

__global__ void prep_x0(const float* __restrict__ mel, _Float16* __restrict__ x0) {
  int idx = blockIdx.x * 256 + threadIdx.x;
  if (idx >= B_ * T_ * XP_) return;
  int k = idx & (XP_ - 1);
  int t = (idx >> 6) % T_;
  int b = idx / (XP_ * T_);
  float v = (k < NMEL_) ? mel[((size_t)b * NMEL_ + k) * T_ + t] : 0.f;
  x0[idx] = (_Float16)v;
}

__global__ void prep_w0(const float* __restrict__ Wih, const float* __restrict__ Whh,
                        _Float16* __restrict__ Wc) {
  int idx = blockIdx.x * 256 + threadIdx.x;
  if (idx >= G4_ * K0_) return;
  int k = idx % K0_;
  int n = idx / K0_;
  float v = 0.f;
  if (k < NMEL_)      v = Wih[(size_t)n * NMEL_ + k];
  else if (k >= XP_)  v = Whh[(size_t)n * H_ + (k - XP_)];
  Wc[idx] = (_Float16)v;
}

__global__ void prep_w12(const float* __restrict__ Wih, const float* __restrict__ Whh,
                         _Float16* __restrict__ Wc) {
  int idx = blockIdx.x * 256 + threadIdx.x;
  if (idx >= G4_ * K12_) return;
  int k = idx % K12_;
  int n = idx / K12_;
  float v = (k < H_) ? Wih[(size_t)n * H_ + k] : Whh[(size_t)n * H_ + (k - H_)];
  Wc[idx] = (_Float16)v;
}

__global__ void prep_bias(const float* __restrict__ bih, const float* __restrict__ bhh,
                          float* __restrict__ bias) {
  int idx = blockIdx.x * 256 + threadIdx.x;
  if (idx < G4_) bias[idx] = bih[idx] + bhh[idx];
}

// Tail W tiles for layers 1/2 own-h streaming: Wt[l2][tile][ci][r 0..63][32],
// r -> gate=(r>>4), unit=(r&15); k = ci*32 + g*8 into the Whh half.
__global__ void prep_wtile(const float* __restrict__ Whh1, const float* __restrict__ Whh2,
                           _Float16* __restrict__ Wt) {
  int idx = blockIdx.x * 256 + threadIdx.x;      // one thread per 8 halfs
  const int total = 2 * NB_ * 24 * 64 * 4;
  if (idx >= total) return;
  int g = idx & 3;
  int r = (idx >> 2) & 63;
  int rest = idx >> 8;
  int ci = rest % 24;
  int rest2 = rest / 24;
  int tile = rest2 % NB_;
  int l2 = rest2 / NB_;
  const float* Whh = l2 ? Whh2 : Whh1;
  int n = (r >> 4) * H_ + tile * 16 + (r & 15);
  int k = ci * 32 + g * 8;
  _Float16 tmp[8];
  for (int u = 0; u < 8; ++u) tmp[u] = (_Float16)Whh[(size_t)n * H_ + k + u];
  *(half8*)(Wt + (((((size_t)l2 * NB_ + tile) * 24 + ci) * 64 + r) * 32 + g * 8)) = *(half8*)tmp;
}

// ---------------- persistent LSTM ----------------

// Per-block completion slots: fl[((s*3)+lp)*96 + blk]; release-stored 1 when
// block blk of layer lp finished grid-step s. 48 blocks/layer -> one 64-lane poll.
// Agent-scope atomic loads read the coherence point (R7-verified, no fences).
__device__ __forceinline__ void wait_group(int* fl, int sp, int lp, int lane) {
  if (lp < 0 || lp > 2) return;
  if (sp < lp || sp > lp + T_ - 1) return;
  const int base = (sp * 3 + lp) * 96;
  int spin = 0;
  for (;;) {
    int v0 = (lane < NB_)
                 ? __hip_atomic_load(&fl[base + lane], __ATOMIC_RELAXED,
                                     __HIP_MEMORY_SCOPE_AGENT) : 1;
    if (__all(v0 != 0)) break;
    __builtin_amdgcn_s_sleep(1);
    if (++spin > 2000000) break;     // bounded: fail as absmax, not hang
  }
}

// K-phase, W resident in LDS (XOR-swizzled quarters), A via DMA-LDS ring.
// vmcnt discipline: chunk c landed after waiting to 2*min(NSTG-1, NC-1-c).
template <int NT, int NSTG, int NC, int AUX>
__device__ __forceinline__ void gemm_phase(
    const _Float16* __restrict__ lwW, int wchunk0, _Float16* __restrict__ lwA,
    const char* __restrict__ src, int strideE,
    int m0, int lane, floatx4 (&acc)[2][NT]) {
  const int lr = lane & 15, quad = lane >> 4;
  const int rrow = lane >> 2, rq = lane & 3;       // lane -> (row, 16B-quarter)
  const int rqs = rq ^ ((rrow >> 1) & 3);          // swizzled global quarter
  const size_t o0 = ((size_t)(m0 + rrow) * strideE + rqs * 8) * 2;
  const size_t o1 = ((size_t)(m0 + 16 + rrow) * strideE + rqs * 8) * 2;

  auto issue = [&](int c) {
    const int slot = c % NSTG;
    char* ld = (char*)lwA + ((size_t)slot * 320 + m0) * 64;   // wave-private slab
    const char* g = src + (size_t)c * 64;
    dma16<AUX>(g + o0, ld);
    dma16<AUX>(g + o1, ld + 1024);
  };

#pragma unroll
  for (int p = 0; p < (NSTG < NC ? NSTG : NC); ++p) issue(p);

  const int asw = (quad ^ ((lr >> 1) & 3)) * 8;    // A-read swizzled quarter

#pragma unroll
  for (int c = 0; c < NC; ++c) {
    const int rem = NC - 1 - c;
    if (rem >= NSTG - 1)      waitvm<2 * (NSTG - 1)>();
    else if (rem == 1)        waitvm<2>();
    else                      waitvm<0>();
    const int slot = c % NSTG;
    const _Float16* aB = lwA + ((size_t)slot * 320 + m0 + lr) * 32 + asw;
    half8 a0 = *(const half8*)(aB);
    half8 a1 = *(const half8*)(aB + 16 * 32);
    half8 bf[NT];
#pragma unroll
    for (int nt = 0; nt < NT; ++nt)
      bf[nt] = *(const half8*)(lwW +
               ((size_t)((wchunk0 + c) * NT * 16 + nt * 16 + lr) * 32 + asw));
#pragma unroll
    for (int nt = 0; nt < NT; ++nt) {
      acc[0][nt] = __builtin_amdgcn_mfma_f32_16x16x32_f16(a0, bf[nt], acc[0][nt], 0, 0, 0);
      acc[1][nt] = __builtin_amdgcn_mfma_f32_16x16x32_f16(a1, bf[nt], acc[1][nt], 0, 0, 0);
    }
    if (c + NSTG < NC) issue(c + NSTG);
  }
}

// K-phase with STREAMED W (global tiles -> VGPR asm ring, normal-cached /
// L2-resident) + A DMA-LDS ring (sc0|sc1). 6 vm-ops per chunk; chunk c landed
// after waiting to 6*min(NSTG-1, NC-1-c) outstanding.
template <int NSTG, int NC>
__device__ __forceinline__ void gemm_ws(
    _Float16* __restrict__ lwA,
    const char* __restrict__ src, int strideE,
    const _Float16* __restrict__ wt,
    int m0, int lane, floatx4 (&acc)[2][4]) {
  const int lr = lane & 15, quad = lane >> 4;
  const int rrow = lane >> 2, rq = lane & 3;
  const int rqs = rq ^ ((rrow >> 1) & 3);
  const size_t o0 = ((size_t)(m0 + rrow) * strideE + rqs * 8) * 2;
  const size_t o1 = ((size_t)(m0 + 16 + rrow) * strideE + rqs * 8) * 2;
  const _Float16* wbase = wt + (size_t)lr * 32 + quad * 8;

  half8 wbuf[NSTG][4];

  auto issue = [&](int c) {
    const int slot = c % NSTG;
    char* ld = (char*)lwA + ((size_t)slot * 320 + m0) * 64;
    const char* g = src + (size_t)c * 64;
    dma16<17>(g + o0, ld);
    dma16<17>(g + o1, ld + 1024);
    const _Float16* wp = wbase + (size_t)c * 64 * 32;
#pragma unroll
    for (int nt = 0; nt < 4; ++nt)
      wbuf[slot][nt] = aload(wp + nt * 16 * 32);
  };

#pragma unroll
  for (int p = 0; p < (NSTG < NC ? NSTG : NC); ++p) issue(p);

  const int asw = (quad ^ ((lr >> 1) & 3)) * 8;

#pragma unroll
  for (int c = 0; c < NC; ++c) {
    const int rem = NC - 1 - c;
    if (rem >= NSTG - 1)      waitvm<6 * (NSTG - 1)>();
    else if (rem == 1)        waitvm<6>();
    else                      waitvm<0>();
    __builtin_amdgcn_sched_barrier(0);             // nothing hoists above the wait
    const int slot = c % NSTG;
    const _Float16* aB = lwA + ((size_t)slot * 320 + m0 + lr) * 32 + asw;
    half8 a0 = *(const half8*)(aB);
    half8 a1 = *(const half8*)(aB + 16 * 32);
#pragma unroll
    for (int nt = 0; nt < 4; ++nt) {
      acc[0][nt] = __builtin_amdgcn_mfma_f32_16x16x32_f16(a0, wbuf[slot][nt], acc[0][nt], 0, 0, 0);
      acc[1][nt] = __builtin_amdgcn_mfma_f32_16x16x32_f16(a1, wbuf[slot][nt], acc[1][nt], 0, 0, 0);
    }
    if (c + NSTG < NC) issue(c + NSTG);
  }
}

__global__ __launch_bounds__(640)
void lstm_persist(const _Float16* __restrict__ x0,
                  const _Float16* __restrict__ Wc0, const _Float16* __restrict__ Wc1,
                  const _Float16* __restrict__ Wc2, const _Float16* __restrict__ Wt,
                  const float* __restrict__ bias, _Float16* __restrict__ hbuf,
                  int* __restrict__ flags) {
  extern __shared__ _Float16 lw[];
  const int bid = blockIdx.x;

  int layer, tile, wlds, K;
  const _Float16* Wsrc;
  if (bid < NB_)            { layer = 0; tile = bid;           wlds = 26;     K = K0_;  Wsrc = Wc0; }
  else if (bid < 2 * NB_)   { layer = 1; tile = bid - NB_;     wlds = WLDS12; K = K12_; Wsrc = Wc1; }
  else                      { layer = 2; tile = bid - 2 * NB_; wlds = WLDS12; K = K12_; Wsrc = Wc2; }
  const int j0 = tile * 16;
  _Float16* lwA = lw + (size_t)wlds * 64 * 32;    // A-ring after resident W
  const _Float16* wt = Wt + ((size_t)((layer - 1) * NB_ + tile) * 24) * 64 * 32;

  // one-time: stage resident W chunks into LDS, chunk-major + XOR-swizzled quarters
  {
    const int total = wlds * 64 * 4;
    for (int idx = threadIdx.x; idx < total; idx += 640) {
      int c = idx >> 8;            // /(64*4)
      int rem = idx & 255;
      int r = rem >> 2;
      int q = rem & 3;
      int grow = (r >> 4) * H_ + j0 + (r & 15);
      half8 v = *(const half8*)(Wsrc + (size_t)grow * K + c * 32 + q * 8);
      int qs = q ^ ((r >> 1) & 3);
      *(half8*)(lw + ((size_t)(c * 64 + r) * 32 + qs * 8)) = v;
    }
  }
  __syncthreads();

  const int lane = threadIdx.x & 63;
  const int wv = threadIdx.x >> 6;      // 10 waves
  const int lr = lane & 15;
  const int quad = lane >> 4;
  const int m0 = wv * 32;
  const int m1 = wv * 32 + 16;
  const int j = j0 + lr;

  const float bI = bias[layer * G4_ + 0 * H_ + j];
  const float bF = bias[layer * G4_ + 1 * H_ + j];
  const float bG = bias[layer * G4_ + 2 * H_ + j];
  const float bO = bias[layer * G4_ + 3 * H_ + j];

  float cst[2][4] = {{0.f, 0.f, 0.f, 0.f}, {0.f, 0.f, 0.f, 0.f}};

  for (int t = 0; t < T_; ++t) {
    const int s = layer + t;
    const int pprev = (s - 1) & (NP_ - 1);
    const int pcur = s & (NP_ - 1);
    const _Float16* hown = hbuf + (size_t)(layer * NP_ + pprev) * B_ * H_;
    _Float16* hout = hbuf + (size_t)(layer * NP_ + pcur) * B_ * H_;

    floatx4 acc0[2][4];
#pragma unroll
    for (int a = 0; a < 2; ++a)
#pragma unroll
      for (int b = 0; b < 4; ++b) acc0[a][b] = (floatx4){0.f, 0.f, 0.f, 0.f};

    if (layer == 0) {
      // x-phase: x0 constant -> no wait; normal-cached
      const char* xsrc = (const char*)(x0 + (size_t)t * XP_);
      gemm_phase<4, 2, 2, 0>(lw, 0, lwA, xsrc, T_ * XP_, m0, lane, acc0);
      // own-h phase (W chunks 2..25 resident); h via coherence point
      wait_group(flags, s - 1, 0, lane);
      gemm_phase<4, 2, 24, 17>(lw, 2, lwA, (const char*)hown, H_, m0, lane, acc0);
    } else {
      // x-phase: W chunks 0..23 resident; A = h_{l-1} via coherence point
      wait_group(flags, s - 1, layer - 1, lane);
      const char* xsrc = (const char*)(hbuf + (size_t)((layer - 1) * NP_ + pprev) * B_ * H_);
      gemm_phase<4, 3, 24, 17>(lw, 0, lwA, xsrc, H_, m0, lane, acc0);
      // own-h phase: W streamed (L2-resident, normal-cached); A = h_l
      wait_group(flags, s - 1, layer, lane);
      gemm_ws<3, 24>(lwA, (const char*)hown, H_, wt, m0, lane, acc0);
    }

    // anti-dep (4-parity): (l+1) readers of parity (s&3) ran at their step s-3.
    wait_group(flags, s - 3, layer + 1, lane);

#pragma unroll
    for (int mt = 0; mt < 2; ++mt)
#pragma unroll
      for (int r = 0; r < 4; ++r) {
        float iv = acc0[mt][0][r] + bI;
        float fv = acc0[mt][1][r] + bF;
        float gv = acc0[mt][2][r] + bG;
        float ov = acc0[mt][3][r] + bO;
        float cn = sigm(fv) * cst[mt][r] + sigm(iv) * tanh_f(gv);
        cst[mt][r] = cn;
        int m = (mt ? m1 : m0) + quad * 4 + r;
        hout[(size_t)m * H_ + j] = (_Float16)(sigm(ov) * tanh_f(cn));
      }

    __syncthreads();   // drains vmcnt (all waves' stores) before release
    if (threadIdx.x == 0)
      __hip_atomic_store(&flags[(s * 3 + layer) * 96 + tile], 1, __ATOMIC_RELEASE,
                         __HIP_MEMORY_SCOPE_AGENT);
  }
}

// ---------------- projection + normalize ----------------
__global__ void dvec_kernel(const _Float16* __restrict__ hlast, const float* __restrict__ Wproj,
                            const float* __restrict__ bproj, float* __restrict__ d3) {
  const int m = blockIdx.x;
  const int d = threadIdx.x;
  const _Float16* h = hlast + (size_t)m * H_;
  const float* w = Wproj + (size_t)d * H_;
  float acc = bproj[d];
  for (int k = 0; k < H_; k++) acc += (float)h[k] * w[k];
  __shared__ float red[256];
  red[d] = acc * acc;
  __syncthreads();
  for (int off = 128; off > 0; off >>= 1) {
    if (d < off) red[d] += red[d + off];
    __syncthreads();
  }
  float nrm = sqrtf(red[0]);
  d3[(size_t)m * D_ + d] = acc / nrm;
}

// ---------------- GE2E ----------------
__device__ float block_reduce_sum(float x, float* red) {
  const int d = threadIdx.x;
  red[d] = x;
  __syncthreads();
  for (int off = 128; off > 0; off >>= 1) {
    if (d < off) red[d] += red[d + off];
    __syncthreads();
  }
  float r = red[0];
  __syncthreads();
  return r;
}

__global__ void cent_kernel(const float* __restrict__ d3, float* __restrict__ cent,
                            float* __restrict__ ncent) {
  const int sIdx = blockIdx.x;
  const int d = threadIdx.x;
  float acc = 0.f;
  for (int u = 0; u < U_; u++) acc += d3[((size_t)sIdx * U_ + u) * D_ + d];
  acc *= (1.f / U_);
  cent[sIdx * D_ + d] = acc;
  __shared__ float red[256];
  float n2 = block_reduce_sum(acc * acc, red);
  if (d == 0) ncent[sIdx] = fmaxf(sqrtf(n2), 1e-8f);
}

__global__ void ge2e_kernel(const float* __restrict__ d3, const float* __restrict__ cent,
                            const float* __restrict__ ncent, const float* __restrict__ loss_w,
                            const float* __restrict__ loss_b, float* __restrict__ accums) {
  const int p = blockIdx.x;
  const int sIdx = p / U_;
  const int d = threadIdx.x;
  __shared__ float red[256];
  __shared__ float sims[S_];

  const float v = d3[(size_t)p * D_ + d];
  const float cs = cent[sIdx * D_ + d];
  const float pc = (cs * U_ - v) * (1.f / (U_ - 1));

  float nv2 = block_reduce_sum(v * v, red);
  float npc2 = block_reduce_sum(pc * pc, red);
  float dotp = block_reduce_sum(v * pc, red);

  const float w = loss_w[0], b = loss_b[0];
  const float na = fmaxf(sqrtf(nv2), 1e-6f);
  const float npc = fmaxf(sqrtf(npc2), 1e-6f);
  const float pos_sim = w * (dotp / (na * npc)) + b;
  const float nd = fmaxf(sqrtf(nv2), 1e-8f);

  for (int k = 0; k < S_; k++) {
    float dk = block_reduce_sum(v * cent[k * D_ + d], red);
    if (d == 0) sims[k] = w * (dk / (nd * ncent[k])) + b;
  }
  __syncthreads();
  if (d == 0) {
    float mx = -1e30f;
    for (int k = 0; k < S_; k++)
      if (k != sIdx) mx = fmaxf(mx, sims[k]);
    float se = 0.f, sn = 0.f;
    for (int k = 0; k < S_; k++)
      if (k != sIdx) { se += expf(sims[k] - mx); sn += sims[k]; }
    float lse = mx + logf(se);
    atomicAdd(&accums[0], -pos_sim + lse);
    atomicAdd(&accums[1], pos_sim);
    atomicAdd(&accums[2], sn);
  }
}

__global__ void finalize_kernel(const float* __restrict__ accums, float* __restrict__ out) {
  if (threadIdx.x == 0) {
    out[0] = accums[0] / (float)(S_ * U_);
    out[1] = accums[1] / (float)(S_ * U_);
    out[2] = accums[2] / (float)(S_ * U_ * (S_ - 1));
  }
}

// ---------------- launch ----------------
extern "C" void kernel_launch(void* const* d_in, const int* in_sizes, int n_in,
                              void* d_out, int out_size, void* d_ws, size_t ws_size,
                              hipStream_t stream) {
  const float* mel = (const float*)d_in[0];
  const float* Wih[3] = {(const float*)d_in[1], (const float*)d_in[5], (const float*)d_in[9]};
  const float* Whh[3] = {(const float*)d_in[2], (const float*)d_in[6], (const float*)d_in[10]};
  const float* bih[3] = {(const float*)d_in[3], (const float*)d_in[7], (const float*)d_in[11]};
  const float* bhh[3] = {(const float*)d_in[4], (const float*)d_in[8], (const float*)d_in[12]};
  const float* Wproj = (const float*)d_in[13];
  const float* bproj = (const float*)d_in[14];
  const float* loss_w = (const float*)d_in[15];
  const float* loss_b = (const float*)d_in[16];
  float* out = (float*)d_out;

  char* ws = (char*)d_ws;
  size_t off = 0;
  auto alloc = [&](size_t bytes) -> void* {
    void* p = ws + off;
    off = (off + bytes + 255) & ~(size_t)255;
    return p;
  };
  _Float16* x0   = (_Float16*)alloc((size_t)B_ * T_ * XP_ * 2);
  _Float16* Wc0  = (_Float16*)alloc((size_t)G4_ * K0_ * 2);
  _Float16* Wc1  = (_Float16*)alloc((size_t)G4_ * K12_ * 2);
  _Float16* Wc2  = (_Float16*)alloc((size_t)G4_ * K12_ * 2);
  _Float16* Wt   = (_Float16*)alloc((size_t)2 * NB_ * 24 * 64 * 32 * 2);
  float*    bias = (float*)alloc((size_t)3 * G4_ * 4);
  _Float16* hbuf = (_Float16*)alloc((size_t)3 * NP_ * B_ * H_ * 2);
  float*    d3   = (float*)alloc((size_t)B_ * D_ * 4);
  float*    cent = (float*)alloc((size_t)S_ * D_ * 4);
  float*    ncent = (float*)alloc((size_t)S_ * 4);
  float*    accums = (float*)alloc(64);
  int*      flags = (int*)alloc((size_t)(T_ + 3) * 3 * 96 * 4);

  hipMemsetAsync(hbuf, 0, (size_t)3 * NP_ * B_ * H_ * 2, stream);
  hipMemsetAsync(accums, 0, 64, stream);
  hipMemsetAsync(flags, 0, (size_t)(T_ + 3) * 3 * 96 * 4, stream);

  prep_x0<<<(B_ * T_ * XP_ + 255) / 256, 256, 0, stream>>>(mel, x0);
  prep_w0<<<(G4_ * K0_ + 255) / 256, 256, 0, stream>>>(Wih[0], Whh[0], Wc0);
  prep_w12<<<(G4_ * K12_ + 255) / 256, 256, 0, stream>>>(Wih[1], Whh[1], Wc1);
  prep_w12<<<(G4_ * K12_ + 255) / 256, 256, 0, stream>>>(Wih[2], Whh[2], Wc2);
  prep_wtile<<<(2 * NB_ * 24 * 64 * 4 + 255) / 256, 256, 0, stream>>>(Whh[1], Whh[2], Wt);
  for (int l = 0; l < 3; l++)
    prep_bias<<<(G4_ + 255) / 256, 256, 0, stream>>>(bih[l], bhh[l], bias + l * G4_);

  hipFuncSetAttribute((const void*)lstm_persist,
                      hipFuncAttributeMaxDynamicSharedMemorySize, SMEM_BYTES);
  void* kargs[] = {(void*)&x0, (void*)&Wc0, (void*)&Wc1, (void*)&Wc2, (void*)&Wt,
                   (void*)&bias, (void*)&hbuf, (void*)&flags};
  hipLaunchCooperativeKernel((const void*)lstm_persist, dim3(NBLK), dim3(640),
                             kargs, SMEM_BYTES, stream);

  // layer-2 final h: s = 2 + 119 = 121 -> parity 121 & 3 = 1
  const _Float16* hlast = hbuf + (size_t)(2 * NP_ + 1) * B_ * H_;
  dvec_kernel<<<B_, 256, 0, stream>>>(hlast, Wproj, bproj, d3);
  cent_kernel<<<S_, 256, 0, stream>>>(d3, cent, ncent);
  ge2e_kernel<<<B_, 256, 0, stream>>>(d3, cent, ncent, loss_w, loss_b, accums);
  finalize_kernel<<<1, 64, 0, stream>>>(accums, out);
}

// Round 9
// 3330.709 us; speedup vs baseline: 1.7929x; 1.7929x over previous
//
#include <hip/hip_runtime.h>
#include <math.h>

// Problem constants
#define S_    32
#define U_    10
#define B_    320           // S*U sequences
#define T_    120
#define NMEL_ 40
#define H_    768
#define G4_   3072          // 4*H gates
#define D_    256
#define XP_   64            // mel features zero-padded 40 -> 64
#define K0_   (XP_ + H_)    // 832, layer-0 fused K
#define K12_  (2 * H_)      // 1536, layers 1/2 fused K
#define NP_   4             // h-buffer parities (staleness window for leader-inv)

#define NB0   48            // layer-0 blocks (16 units each)
#define NB12  96            // layer-1/2 blocks (8 units each)
#define NBLK  (NB0 + 2 * NB12)  // 240 blocks, 1 per CU

// LDS: weights chunk-major, 64 B rows, XOR-swizzled quarters; then A-stage ring.
// layers 1/2: 48*32*64 = 98,304 weights + 3*20,480 ring = 159,744
// layer 0:    26*64*64 = 106,496 weights + 2*20,480 ring = 147,456
#define SMEM_BYTES 159744

typedef _Float16 half8 __attribute__((ext_vector_type(8)));
typedef float floatx4 __attribute__((ext_vector_type(4)));

__device__ __forceinline__ float sigm(float x) {
  return 1.f / (1.f + __expf(-x));
}
__device__ __forceinline__ float tanh_f(float x) {
  x = fminf(15.f, fmaxf(-15.f, x));
  float e = __expf(2.f * x);
  return (e - 1.f) / (e + 1.f);
}

// async global->LDS DMA, 16 B per lane; LDS dest = wave-uniform base + lane*16.
// AUX=1 -> sc0: bypass CU-private L1 (h freshness under leader-only inv;
// the leader's fence cleans only ITS CU's L1). AUX=0: normal (constant x0).
template <int AUX>
__device__ __forceinline__ void dma16(const void* g, void* l) {
  __builtin_amdgcn_global_load_lds(
      (const __attribute__((address_space(1))) unsigned int*)g,
      (__attribute__((address_space(3))) unsigned int*)l, 16, 0, AUX);
}

// s_waitcnt vmcnt(N) only (expcnt/lgkmcnt all-ones = no wait)
template <int N>
__device__ __forceinline__ void waitvm() {
  __builtin_amdgcn_s_waitcnt(0x3FF0 | (N & 0xF) | ((N >> 4) << 14));
}

// ---------------- prep kernels ----------------

__global__ void prep_x0(const float* __restrict__ mel, _Float16* __restrict__ x0) {
  int idx = blockIdx.x * 256 + threadIdx.x;
  if (idx >= B_ * T_ * XP_) return;
  int k = idx & (XP_ - 1);
  int t = (idx >> 6) % T_;
  int b = idx / (XP_ * T_);
  float v = (k < NMEL_) ? mel[((size_t)b * NMEL_ + k) * T_ + t] : 0.f;
  x0[idx] = (_Float16)v;
}

__global__ void prep_w0(const float* __restrict__ Wih, const float* __restrict__ Whh,
                        _Float16* __restrict__ Wc) {
  int idx = blockIdx.x * 256 + threadIdx.x;
  if (idx >= G4_ * K0_) return;
  int k = idx % K0_;
  int n = idx / K0_;
  float v = 0.f;
  if (k < NMEL_)      v = Wih[(size_t)n * NMEL_ + k];
  else if (k >= XP_)  v = Whh[(size_t)n * H_ + (k - XP_)];
  Wc[idx] = (_Float16)v;
}

__global__ void prep_w12(const float* __restrict__ Wih, const float* __restrict__ Whh,
                         _Float16* __restrict__ Wc) {
  int idx = blockIdx.x * 256 + threadIdx.x;
  if (idx >= G4_ * K12_) return;
  int k = idx % K12_;
  int n = idx / K12_;
  float v = (k < H_) ? Wih[(size_t)n * H_ + k] : Whh[(size_t)n * H_ + (k - H_)];
  Wc[idx] = (_Float16)v;
}

__global__ void prep_bias(const float* __restrict__ bih, const float* __restrict__ bhh,
                          float* __restrict__ bias) {
  int idx = blockIdx.x * 256 + threadIdx.x;
  if (idx < G4_) bias[idx] = bih[idx] + bhh[idx];
}

// ---------------- persistent LSTM ----------------

// Per-block completion slots: fl[((s*3)+lp)*96 + blk]; release-stored 1 when
// block blk of layer lp finished grid-step s. Wave-parallel polling (any wave).
__device__ __forceinline__ void wait_group(int* fl, int sp, int lp, int lane) {
  if (lp < 0 || lp > 2) return;
  if (sp < lp || sp > lp + T_ - 1) return;
  const int tgt = (lp == 0) ? NB0 : NB12;
  const int base = (sp * 3 + lp) * 96;
  int spin = 0;
  for (;;) {
    int v0 = (lane < tgt)
                 ? __hip_atomic_load(&fl[base + lane], __ATOMIC_RELAXED,
                                     __HIP_MEMORY_SCOPE_AGENT) : 1;
    int v1 = (lane + 64 < tgt)
                 ? __hip_atomic_load(&fl[base + 64 + lane], __ATOMIC_RELAXED,
                                     __HIP_MEMORY_SCOPE_AGENT) : 1;
    if (__all(v0 != 0 && v1 != 0)) break;
    __builtin_amdgcn_s_sleep(1);
    if (++spin > 2000000) break;     // bounded: fail as absmax, not hang
  }
}

// ONE merged K-ring per step: chunks 0..CSPLIT-1 from srcX, CSPLIT..NC-1 from
// srcH. W chunk index = c (fused-K layout already matches). The own-layer flag
// wait fires exactly once, inside the loop, before the first h-chunk DMA ->
// no mid-step ring drain / cold restart (this is the R9 change vs R4).
// vmcnt discipline: chunk c landed after waiting to 2*min(NSTG-1, NC-1-c).
template <int NT, int NSTG, int NC, int CSPLIT, int AUXX, int AUXH>
__device__ __forceinline__ void gemm_merged(
    const _Float16* __restrict__ lwW, _Float16* __restrict__ lwA,
    const char* __restrict__ srcX, int strideX,
    const char* __restrict__ srcH, int strideH,
    int m0, int lane, floatx4 (&acc)[2][NT],
    int* __restrict__ flags, int sprev, int layer) {
  const int lr = lane & 15, quad = lane >> 4;
  const int rrow = lane >> 2, rq = lane & 3;       // lane -> (row, 16B-quarter)
  const int rqs = rq ^ ((rrow >> 1) & 3);          // swizzled global quarter
  const size_t ox0 = ((size_t)(m0 + rrow) * strideX + rqs * 8) * 2;
  const size_t ox1 = ((size_t)(m0 + 16 + rrow) * strideX + rqs * 8) * 2;
  const size_t oh0 = ((size_t)(m0 + rrow) * strideH + rqs * 8) * 2;
  const size_t oh1 = ((size_t)(m0 + 16 + rrow) * strideH + rqs * 8) * 2;

  auto issue = [&](int c) {
    const int slot = c % NSTG;
    char* ld = (char*)lwA + ((size_t)slot * 320 + m0) * 64;   // wave-private slab
    if (c < CSPLIT) {
      const char* g = srcX + (size_t)c * 64;
      dma16<AUXX>(g + ox0, ld);
      dma16<AUXX>(g + ox1, ld + 1024);
    } else {
      const char* g = srcH + (size_t)(c - CSPLIT) * 64;
      dma16<AUXH>(g + oh0, ld);
      dma16<AUXH>(g + oh1, ld + 1024);
    }
  };

#pragma unroll
  for (int p = 0; p < NSTG; ++p) issue(p);   // all < CSPLIT by construction

  const int asw = (quad ^ ((lr >> 1) & 3)) * 8;    // A-read swizzled quarter

#pragma unroll
  for (int c = 0; c < NC; ++c) {
    const int rem = NC - 1 - c;                    // chunks issued after c
    if (rem >= NSTG - 1)      waitvm<2 * (NSTG - 1)>();
    else if (rem == 1)        waitvm<2>();
    else                      waitvm<0>();
    const int slot = c % NSTG;
    const _Float16* aB = lwA + ((size_t)slot * 320 + m0 + lr) * 32 + asw;
    half8 a0 = *(const half8*)(aB);
    half8 a1 = *(const half8*)(aB + 16 * 32);
    half8 bf[NT];
#pragma unroll
    for (int nt = 0; nt < NT; ++nt)
      bf[nt] = *(const half8*)(lwW +
               ((size_t)(c * NT * 16 + nt * 16 + lr) * 32 + asw));
#pragma unroll
    for (int nt = 0; nt < NT; ++nt) {
      acc[0][nt] = __builtin_amdgcn_mfma_f32_16x16x32_f16(a0, bf[nt], acc[0][nt], 0, 0, 0);
      acc[1][nt] = __builtin_amdgcn_mfma_f32_16x16x32_f16(a1, bf[nt], acc[1][nt], 0, 0, 0);
    }
    if (c + NSTG < NC) {
      if (c + NSTG == CSPLIT)                      // once: before 1st h-chunk DMA
        wait_group(flags, sprev, layer, lane);
      issue(c + NSTG);
    }
  }
}

__global__ __launch_bounds__(640)
void lstm_persist(const _Float16* __restrict__ x0,
                  const _Float16* __restrict__ Wc0, const _Float16* __restrict__ Wc1,
                  const _Float16* __restrict__ Wc2,
                  const float* __restrict__ bias, _Float16* __restrict__ hbuf,
                  int* __restrict__ flags, int* __restrict__ tick,
                  int* __restrict__ leadDone) {
  extern __shared__ _Float16 lw[];
  const int bid = blockIdx.x;

  int layer, tile, units, K;
  const _Float16* Wsrc;
  if (bid < NB0)            { layer = 0; tile = bid;              units = 16; K = K0_;  Wsrc = Wc0; }
  else if (bid < NB0+NB12)  { layer = 1; tile = bid - NB0;        units = 8;  K = K12_; Wsrc = Wc1; }
  else                      { layer = 2; tile = bid - NB0 - NB12; units = 8;  K = K12_; Wsrc = Wc2; }
  const int nrows = units * 4;
  const int j0 = tile * units;
  _Float16* lwA = lw + (size_t)(K / 32) * nrows * 32;   // A-ring after weights

  unsigned xcc;
  asm volatile("s_getreg_b32 %0, hwreg(HW_REG_XCC_ID)" : "=s"(xcc));
  xcc &= 7;

  // one-time: stage weight slice into LDS, chunk-major + XOR-swizzled quarters
  {
    const int total = (K / 32) * nrows * 4;
    for (int idx = threadIdx.x; idx < total; idx += 640) {
      int c = idx / (nrows * 4);
      int rem = idx % (nrows * 4);
      int r = rem >> 2;
      int q = rem & 3;
      int grow = (r / units) * H_ + j0 + (r % units);
      half8 v = *(const half8*)(Wsrc + (size_t)grow * K + c * 32 + q * 8);
      int qs = q ^ ((r >> 1) & 3);
      *(half8*)(lw + ((size_t)(c * nrows + r) * 32 + qs * 8)) = v;
    }
  }
  __syncthreads();

  const int lane = threadIdx.x & 63;
  const int wv = threadIdx.x >> 6;      // 10 waves
  const int lr = lane & 15;
  const int quad = lane >> 4;
  const int m0 = wv * 32;
  const int m1 = wv * 32 + 16;
  const int j = j0 + ((units == 16) ? lr : (lr & 7));

  const float bI = bias[layer * G4_ + 0 * H_ + j];
  const float bF = bias[layer * G4_ + 1 * H_ + j];
  const float bG = bias[layer * G4_ + 2 * H_ + j];
  const float bO = bias[layer * G4_ + 3 * H_ + j];

  float cst[2][4] = {{0.f, 0.f, 0.f, 0.f}, {0.f, 0.f, 0.f, 0.f}};

  for (int t = 0; t < T_; ++t) {
    const int s = layer + t;
    const int pprev = (s - 1) & (NP_ - 1);
    const int pcur = s & (NP_ - 1);
    const _Float16* hown = hbuf + (size_t)(layer * NP_ + pprev) * B_ * H_;
    _Float16* hout = hbuf + (size_t)(layer * NP_ + pcur) * B_ * H_;

    // ---- epoch gate: ONE L2 invalidate per XCD per epoch (leader election).
    // Stale parity lines in this XCD's L2 date from epoch s-4 readers; leader
    // fences of epochs s-3..s-1 removed them (skew < 4 enforced by the s-3
    // anti-dep + s-1 own-h waits). CU-private L1 staleness: sc0 on h loads.
    if (threadIdx.x == 0) {
      if (__hip_atomic_fetch_add(&tick[xcc * 128 + s], 1, __ATOMIC_RELAXED,
                                 __HIP_MEMORY_SCOPE_AGENT) == 0) {
        __builtin_amdgcn_fence(__ATOMIC_ACQUIRE, "agent");   // inv L1+L2
        __hip_atomic_store(&leadDone[xcc * 128 + s], 1, __ATOMIC_RELEASE,
                           __HIP_MEMORY_SCOPE_AGENT);
      }
    }
    if (lane == 0) {
      int spin = 0;
      while (__hip_atomic_load(&leadDone[xcc * 128 + s], __ATOMIC_RELAXED,
                               __HIP_MEMORY_SCOPE_AGENT) == 0) {
        __builtin_amdgcn_s_sleep(1);
        if (++spin > 2000000) break;
      }
    }

    floatx4 acc0[2][4];
    floatx4 acc2[2][2];

    if (layer == 0) {
      // merged ring: chunks 0-1 = x0 (constant, cacheable), 2-25 = own-h (sc0).
      // own-layer flag wait fires inside, before chunk 2's DMA.
#pragma unroll
      for (int a = 0; a < 2; ++a)
#pragma unroll
        for (int b = 0; b < 4; ++b) acc0[a][b] = (floatx4){0.f, 0.f, 0.f, 0.f};
      gemm_merged<4, 2, 26, 2, 0, 1>(lw, lwA,
          (const char*)(x0 + (size_t)t * XP_), T_ * XP_,
          (const char*)hown, H_, m0, lane, acc0, flags, s - 1, 0);
    } else {
      // producer (l-1, s-1) wait, then merged ring: chunks 0-23 = h_{l-1}
      // (Wih half, sc0), 24-47 = own-h (Whh half, sc0); own wait inside at c=24.
      wait_group(flags, s - 1, layer - 1, lane);
#pragma unroll
      for (int a = 0; a < 2; ++a)
#pragma unroll
        for (int b = 0; b < 2; ++b) acc2[a][b] = (floatx4){0.f, 0.f, 0.f, 0.f};
      const char* xsrc = (const char*)(hbuf + (size_t)((layer - 1) * NP_ + pprev) * B_ * H_);
      gemm_merged<2, 3, 48, 24, 1, 1>(lw, lwA,
          xsrc, H_, (const char*)hown, H_, m0, lane, acc2, flags, s - 1, layer);
    }

    // anti-dep (4-parity): (l+1) readers of parity (s&3) ran at their step s-3.
    wait_group(flags, s - 3, layer + 1, lane);

    if (layer == 0) {
#pragma unroll
      for (int mt = 0; mt < 2; ++mt)
#pragma unroll
        for (int r = 0; r < 4; ++r) {
          float iv = acc0[mt][0][r] + bI;
          float fv = acc0[mt][1][r] + bF;
          float gv = acc0[mt][2][r] + bG;
          float ov = acc0[mt][3][r] + bO;
          float cn = sigm(fv) * cst[mt][r] + sigm(iv) * tanh_f(gv);
          cst[mt][r] = cn;
          int m = (mt ? m1 : m0) + quad * 4 + r;
          hout[(size_t)m * H_ + j] = (_Float16)(sigm(ov) * tanh_f(cn));
        }
    } else {
      // tile0 cols: i,f (units 0..7); tile1: g,o. xor-8 colocates the 4 gates.
#pragma unroll
      for (int mt = 0; mt < 2; ++mt)
#pragma unroll
        for (int r = 0; r < 4; ++r) {
          float t0 = acc2[mt][0][r], t1 = acc2[mt][1][r];
          float p0 = __shfl_xor(t0, 8, 64);
          float p1 = __shfl_xor(t1, 8, 64);
          bool lo = (lr < 8);
          float iv = (lo ? t0 : p0) + bI;
          float fv = (lo ? p0 : t0) + bF;
          float gv = (lo ? t1 : p1) + bG;
          float ov = (lo ? p1 : t1) + bO;
          float cn = sigm(fv) * cst[mt][r] + sigm(iv) * tanh_f(gv);
          cst[mt][r] = cn;
          if (lo) {
            int m = (mt ? m1 : m0) + quad * 4 + r;
            hout[(size_t)m * H_ + j] = (_Float16)(sigm(ov) * tanh_f(cn));
          }
        }
    }

    __syncthreads();   // drains vmcnt (all waves' stores) before release
    if (threadIdx.x == 0)
      __hip_atomic_store(&flags[(s * 3 + layer) * 96 + tile], 1, __ATOMIC_RELEASE,
                         __HIP_MEMORY_SCOPE_AGENT);
  }
}

// ---------------- projection + normalize ----------------
__global__ void dvec_kernel(const _Float16* __restrict__ hlast, const float* __restrict__ Wproj,
                            const float* __restrict__ bproj, float* __restrict__ d3) {
  const int m = blockIdx.x;
  const int d = threadIdx.x;
  const _Float16* h = hlast + (size_t)m * H_;
  const float* w = Wproj + (size_t)d * H_;
  float acc = bproj[d];
  for (int k = 0; k < H_; k++) acc += (float)h[k] * w[k];
  __shared__ float red[256];
  red[d] = acc * acc;
  __syncthreads();
  for (int off = 128; off > 0; off >>= 1) {
    if (d < off) red[d] += red[d + off];
    __syncthreads();
  }
  float nrm = sqrtf(red[0]);
  d3[(size_t)m * D_ + d] = acc / nrm;
}

// ---------------- GE2E ----------------
__device__ float block_reduce_sum(float x, float* red) {
  const int d = threadIdx.x;
  red[d] = x;
  __syncthreads();
  for (int off = 128; off > 0; off >>= 1) {
    if (d < off) red[d] += red[d + off];
    __syncthreads();
  }
  float r = red[0];
  __syncthreads();
  return r;
}

__global__ void cent_kernel(const float* __restrict__ d3, float* __restrict__ cent,
                            float* __restrict__ ncent) {
  const int sIdx = blockIdx.x;
  const int d = threadIdx.x;
  float acc = 0.f;
  for (int u = 0; u < U_; u++) acc += d3[((size_t)sIdx * U_ + u) * D_ + d];
  acc *= (1.f / U_);
  cent[sIdx * D_ + d] = acc;
  __shared__ float red[256];
  float n2 = block_reduce_sum(acc * acc, red);
  if (d == 0) ncent[sIdx] = fmaxf(sqrtf(n2), 1e-8f);
}

__global__ void ge2e_kernel(const float* __restrict__ d3, const float* __restrict__ cent,
                            const float* __restrict__ ncent, const float* __restrict__ loss_w,
                            const float* __restrict__ loss_b, float* __restrict__ accums) {
  const int p = blockIdx.x;
  const int sIdx = p / U_;
  const int d = threadIdx.x;
  __shared__ float red[256];
  __shared__ float sims[S_];

  const float v = d3[(size_t)p * D_ + d];
  const float cs = cent[sIdx * D_ + d];
  const float pc = (cs * U_ - v) * (1.f / (U_ - 1));

  float nv2 = block_reduce_sum(v * v, red);
  float npc2 = block_reduce_sum(pc * pc, red);
  float dotp = block_reduce_sum(v * pc, red);

  const float w = loss_w[0], b = loss_b[0];
  const float na = fmaxf(sqrtf(nv2), 1e-6f);
  const float npc = fmaxf(sqrtf(npc2), 1e-6f);
  const float pos_sim = w * (dotp / (na * npc)) + b;
  const float nd = fmaxf(sqrtf(nv2), 1e-8f);

  for (int k = 0; k < S_; k++) {
    float dk = block_reduce_sum(v * cent[k * D_ + d], red);
    if (d == 0) sims[k] = w * (dk / (nd * ncent[k])) + b;
  }
  __syncthreads();
  if (d == 0) {
    float mx = -1e30f;
    for (int k = 0; k < S_; k++)
      if (k != sIdx) mx = fmaxf(mx, sims[k]);
    float se = 0.f, sn = 0.f;
    for (int k = 0; k < S_; k++)
      if (k != sIdx) { se += expf(sims[k] - mx); sn += sims[k]; }
    float lse = mx + logf(se);
    atomicAdd(&accums[0], -pos_sim + lse);
    atomicAdd(&accums[1], pos_sim);
    atomicAdd(&accums[2], sn);
  }
}

__global__ void finalize_kernel(const float* __restrict__ accums, float* __restrict__ out) {
  if (threadIdx.x == 0) {
    out[0] = accums[0] / (float)(S_ * U_);
    out[1] = accums[1] / (float)(S_ * U_);
    out[2] = accums[2] / (float)(S_ * U_ * (S_ - 1));
  }
}

// ---------------- launch ----------------
extern "C" void kernel_launch(void* const* d_in, const int* in_sizes, int n_in,
                              void* d_out, int out_size, void* d_ws, size_t ws_size,
                              hipStream_t stream) {
  const float* mel = (const float*)d_in[0];
  const float* Wih[3] = {(const float*)d_in[1], (const float*)d_in[5], (const float*)d_in[9]};
  const float* Whh[3] = {(const float*)d_in[2], (const float*)d_in[6], (const float*)d_in[10]};
  const float* bih[3] = {(const float*)d_in[3], (const float*)d_in[7], (const float*)d_in[11]};
  const float* bhh[3] = {(const float*)d_in[4], (const float*)d_in[8], (const float*)d_in[12]};
  const float* Wproj = (const float*)d_in[13];
  const float* bproj = (const float*)d_in[14];
  const float* loss_w = (const float*)d_in[15];
  const float* loss_b = (const float*)d_in[16];
  float* out = (float*)d_out;

  char* ws = (char*)d_ws;
  size_t off = 0;
  auto alloc = [&](size_t bytes) -> void* {
    void* p = ws + off;
    off = (off + bytes + 255) & ~(size_t)255;
    return p;
  };
  _Float16* x0   = (_Float16*)alloc((size_t)B_ * T_ * XP_ * 2);
  _Float16* Wc0  = (_Float16*)alloc((size_t)G4_ * K0_ * 2);
  _Float16* Wc1  = (_Float16*)alloc((size_t)G4_ * K12_ * 2);
  _Float16* Wc2  = (_Float16*)alloc((size_t)G4_ * K12_ * 2);
  float*    bias = (float*)alloc((size_t)3 * G4_ * 4);
  _Float16* hbuf = (_Float16*)alloc((size_t)3 * NP_ * B_ * H_ * 2);
  float*    d3   = (float*)alloc((size_t)B_ * D_ * 4);
  float*    cent = (float*)alloc((size_t)S_ * D_ * 4);
  float*    ncent = (float*)alloc((size_t)S_ * 4);
  float*    accums = (float*)alloc(64);
  int*      flags = (int*)alloc((size_t)(T_ + 3) * 3 * 96 * 4);
  int*      tick  = (int*)alloc((size_t)8 * 128 * 4);
  int*      lead  = (int*)alloc((size_t)8 * 128 * 4);

  hipMemsetAsync(hbuf, 0, (size_t)3 * NP_ * B_ * H_ * 2, stream);
  hipMemsetAsync(accums, 0, 64, stream);
  hipMemsetAsync(flags, 0, (size_t)(T_ + 3) * 3 * 96 * 4, stream);
  hipMemsetAsync(tick, 0, (size_t)8 * 128 * 4, stream);
  hipMemsetAsync(lead, 0, (size_t)8 * 128 * 4, stream);

  prep_x0<<<(B_ * T_ * XP_ + 255) / 256, 256, 0, stream>>>(mel, x0);
  prep_w0<<<(G4_ * K0_ + 255) / 256, 256, 0, stream>>>(Wih[0], Whh[0], Wc0);
  prep_w12<<<(G4_ * K12_ + 255) / 256, 256, 0, stream>>>(Wih[1], Whh[1], Wc1);
  prep_w12<<<(G4_ * K12_ + 255) / 256, 256, 0, stream>>>(Wih[2], Whh[2], Wc2);
  for (int l = 0; l < 3; l++)
    prep_bias<<<(G4_ + 255) / 256, 256, 0, stream>>>(bih[l], bhh[l], bias + l * G4_);

  hipFuncSetAttribute((const void*)lstm_persist,
                      hipFuncAttributeMaxDynamicSharedMemorySize, SMEM_BYTES);
  void* kargs[] = {(void*)&x0, (void*)&Wc0, (void*)&Wc1, (void*)&Wc2,
                   (void*)&bias, (void*)&hbuf, (void*)&flags, (void*)&tick,
                   (void*)&lead};
  hipLaunchCooperativeKernel((const void*)lstm_persist, dim3(NBLK), dim3(640),
                             kargs, SMEM_BYTES, stream);

  // layer-2 final h: s = 2 + 119 = 121 -> parity 121 & 3 = 1
  const _Float16* hlast = hbuf + (size_t)(2 * NP_ + 1) * B_ * H_;
  dvec_kernel<<<B_, 256, 0, stream>>>(hlast, Wproj, bproj, d3);
  cent_kernel<<<S_, 256, 0, stream>>>(d3, cent, ncent);
  ge2e_kernel<<<B_, 256, 0, stream>>>(d3, cent, ncent, loss_w, loss_b, accums);
  finalize_kernel<<<1, 64, 0, stream>>>(accums, out);
}

// Round 11
// 3318.961 us; speedup vs baseline: 1.7992x; 1.0035x over previous
//
#include <hip/hip_runtime.h>
#include <math.h>

// Problem constants
#define S_    32
#define U_    10
#define B_    320           // S*U sequences
#define T_    120
#define NMEL_ 40
#define H_    768
#define G4_   3072          // 4*H gates
#define D_    256
#define XP_   64            // mel features zero-padded 40 -> 64
#define K0_   (XP_ + H_)    // 832, layer-0 fused K
#define K12_  (2 * H_)      // 1536, layers 1/2 fused K
#define NP_   4             // h-buffer parities (staleness window for leader-inv)

#define NB0   48            // layer-0 blocks (16 units each)
#define NB12  96            // layer-1/2 blocks (8 units each)
#define NBLK  (NB0 + 2 * NB12)  // 240 blocks, 1 per CU

#define WLDS12 39           // layers 1/2: W chunks resident in LDS
#define NWR12  9            // layers 1/2: W chunks held in registers (c = 39..47)

// LDS: layers 1/2: 39*32*64 = 79,872 W + 4*20,480 ring = 161,792 (<= 160 KiB)
//      layer 0:    26*64*64 = 106,496 W + 2*20,480 ring = 147,456
#define SMEM_BYTES 161792

typedef _Float16 half8 __attribute__((ext_vector_type(8)));
typedef float floatx4 __attribute__((ext_vector_type(4)));

__device__ __forceinline__ float sigm(float x) {
  return 1.f / (1.f + __expf(-x));
}
__device__ __forceinline__ float tanh_f(float x) {
  x = fminf(15.f, fmaxf(-15.f, x));
  float e = __expf(2.f * x);
  return (e - 1.f) / (e + 1.f);
}

// async global->LDS DMA, 16 B per lane; LDS dest = wave-uniform base + lane*16.
// AUX=1 -> sc0: bypass CU-private L1 (h freshness under leader-only inv;
// the leader's fence cleans only ITS CU's L1). AUX=0: normal (constant x0).
template <int AUX>
__device__ __forceinline__ void dma16(const void* g, void* l) {
  __builtin_amdgcn_global_load_lds(
      (const __attribute__((address_space(1))) unsigned int*)g,
      (__attribute__((address_space(3))) unsigned int*)l, 16, 0, AUX);
}

// s_waitcnt vmcnt(N) only (expcnt/lgkmcnt all-ones = no wait)
template <int N>
__device__ __forceinline__ void waitvm() {
  __builtin_amdgcn_s_waitcnt(0x3FF0 | (N & 0xF) | ((N >> 4) << 14));
}

// ---------------- prep kernels ----------------

__global__ void prep_x0(const float* __restrict__ mel, _Float16* __restrict__ x0) {
  int idx = blockIdx.x * 256 + threadIdx.x;
  if (idx >= B_ * T_ * XP_) return;
  int k = idx & (XP_ - 1);
  int t = (idx >> 6) % T_;
  int b = idx / (XP_ * T_);
  float v = (k < NMEL_) ? mel[((size_t)b * NMEL_ + k) * T_ + t] : 0.f;
  x0[idx] = (_Float16)v;
}

__global__ void prep_w0(const float* __restrict__ Wih, const float* __restrict__ Whh,
                        _Float16* __restrict__ Wc) {
  int idx = blockIdx.x * 256 + threadIdx.x;
  if (idx >= G4_ * K0_) return;
  int k = idx % K0_;
  int n = idx / K0_;
  float v = 0.f;
  if (k < NMEL_)      v = Wih[(size_t)n * NMEL_ + k];
  else if (k >= XP_)  v = Whh[(size_t)n * H_ + (k - XP_)];
  Wc[idx] = (_Float16)v;
}

__global__ void prep_w12(const float* __restrict__ Wih, const float* __restrict__ Whh,
                         _Float16* __restrict__ Wc) {
  int idx = blockIdx.x * 256 + threadIdx.x;
  if (idx >= G4_ * K12_) return;
  int k = idx % K12_;
  int n = idx / K12_;
  float v = (k < H_) ? Wih[(size_t)n * H_ + k] : Whh[(size_t)n * H_ + (k - H_)];
  Wc[idx] = (_Float16)v;
}

__global__ void prep_bias(const float* __restrict__ bih, const float* __restrict__ bhh,
                          float* __restrict__ bias) {
  int idx = blockIdx.x * 256 + threadIdx.x;
  if (idx < G4_) bias[idx] = bih[idx] + bhh[idx];
}

// ---------------- persistent LSTM ----------------

// Per-block completion slots: fl[((s*3)+lp)*96 + blk]; release-stored 1 when
// block blk of layer lp finished grid-step s. Wave-parallel polling (any wave).
__device__ __forceinline__ void wait_group(int* fl, int sp, int lp, int lane) {
  if (lp < 0 || lp > 2) return;
  if (sp < lp || sp > lp + T_ - 1) return;
  const int tgt = (lp == 0) ? NB0 : NB12;
  const int base = (sp * 3 + lp) * 96;
  int spin = 0;
  for (;;) {
    int v0 = (lane < tgt)
                 ? __hip_atomic_load(&fl[base + lane], __ATOMIC_RELAXED,
                                     __HIP_MEMORY_SCOPE_AGENT) : 1;
    int v1 = (lane + 64 < tgt)
                 ? __hip_atomic_load(&fl[base + 64 + lane], __ATOMIC_RELAXED,
                                     __HIP_MEMORY_SCOPE_AGENT) : 1;
    if (__all(v0 != 0 && v1 != 0)) break;
    __builtin_amdgcn_s_sleep(1);
    if (++spin > 2000000) break;     // bounded: fail as absmax, not hang
  }
}

// ONE merged K-ring per step: chunks 0..CSPLIT-1 from srcX, CSPLIT..NC-1 from
// srcH. W chunk index = c. Chunks >= NC-NWR take their W fragment from the
// per-wave register array wreg (constant, preloaded once) instead of LDS —
// this is what frees LDS for the 4th ring slot. Own-layer flag wait fires
// once, inside the loop, before the first h-chunk DMA.
// vmcnt discipline: chunk c landed after waiting to 2*min(NSTG-1, NC-1-c).
template <int NT, int NSTG, int NC, int CSPLIT, int AUXX, int AUXH, int NWR>
__device__ __forceinline__ void gemm_merged(
    const _Float16* __restrict__ lwW, _Float16* __restrict__ lwA,
    const char* __restrict__ srcX, int strideX,
    const char* __restrict__ srcH, int strideH,
    int m0, int lane, floatx4 (&acc)[2][NT],
    int* __restrict__ flags, int sprev, int layer,
    const half8 (&wreg)[18]) {
  const int lr = lane & 15, quad = lane >> 4;
  const int rrow = lane >> 2, rq = lane & 3;       // lane -> (row, 16B-quarter)
  const int rqs = rq ^ ((rrow >> 1) & 3);          // swizzled global quarter
  const size_t ox0 = ((size_t)(m0 + rrow) * strideX + rqs * 8) * 2;
  const size_t ox1 = ((size_t)(m0 + 16 + rrow) * strideX + rqs * 8) * 2;
  const size_t oh0 = ((size_t)(m0 + rrow) * strideH + rqs * 8) * 2;
  const size_t oh1 = ((size_t)(m0 + 16 + rrow) * strideH + rqs * 8) * 2;

  auto issue = [&](int c) {
    const int slot = c % NSTG;
    char* ld = (char*)lwA + ((size_t)slot * 320 + m0) * 64;   // wave-private slab
    if (c < CSPLIT) {
      const char* g = srcX + (size_t)c * 64;
      dma16<AUXX>(g + ox0, ld);
      dma16<AUXX>(g + ox1, ld + 1024);
    } else {
      const char* g = srcH + (size_t)(c - CSPLIT) * 64;
      dma16<AUXH>(g + oh0, ld);
      dma16<AUXH>(g + oh1, ld + 1024);
    }
  };

#pragma unroll
  for (int p = 0; p < NSTG; ++p) issue(p);   // all < CSPLIT by construction

  const int asw = (quad ^ ((lr >> 1) & 3)) * 8;    // A-read swizzled quarter

#pragma unroll
  for (int c = 0; c < NC; ++c) {
    const int rem = NC - 1 - c;                    // chunks issued after c
    if (rem >= NSTG - 1)      waitvm<2 * (NSTG - 1)>();
    else if (rem == 2)        waitvm<4>();
    else if (rem == 1)        waitvm<2>();
    else                      waitvm<0>();
    const int slot = c % NSTG;
    const _Float16* aB = lwA + ((size_t)slot * 320 + m0 + lr) * 32 + asw;
    half8 a0 = *(const half8*)(aB);
    half8 a1 = *(const half8*)(aB + 16 * 32);
    half8 bf[NT];
    if (NWR > 0 && c >= NC - NWR) {
#pragma unroll
      for (int nt = 0; nt < NT; ++nt)
        bf[nt] = wreg[(c - (NC - NWR)) * NT + nt];
    } else {
#pragma unroll
      for (int nt = 0; nt < NT; ++nt)
        bf[nt] = *(const half8*)(lwW +
                 ((size_t)(c * NT * 16 + nt * 16 + lr) * 32 + asw));
    }
#pragma unroll
    for (int nt = 0; nt < NT; ++nt) {
      acc[0][nt] = __builtin_amdgcn_mfma_f32_16x16x32_f16(a0, bf[nt], acc[0][nt], 0, 0, 0);
      acc[1][nt] = __builtin_amdgcn_mfma_f32_16x16x32_f16(a1, bf[nt], acc[1][nt], 0, 0, 0);
    }
    if (c + NSTG < NC) {
      if (c + NSTG == CSPLIT)                      // once: before 1st h-chunk DMA
        wait_group(flags, sprev, layer, lane);
      issue(c + NSTG);
    }
  }
}

__global__ __launch_bounds__(640, 3)
void lstm_persist(const _Float16* __restrict__ x0,
                  const _Float16* __restrict__ Wc0, const _Float16* __restrict__ Wc1,
                  const _Float16* __restrict__ Wc2,
                  const float* __restrict__ bias, _Float16* __restrict__ hbuf,
                  int* __restrict__ flags, int* __restrict__ tick,
                  int* __restrict__ leadDone) {
  extern __shared__ _Float16 lw[];
  const int bid = blockIdx.x;

  int layer, tile, units, K, wlds;
  const _Float16* Wsrc;
  if (bid < NB0)            { layer = 0; tile = bid;              units = 16; K = K0_;  wlds = 26;     Wsrc = Wc0; }
  else if (bid < NB0+NB12)  { layer = 1; tile = bid - NB0;        units = 8;  K = K12_; wlds = WLDS12; Wsrc = Wc1; }
  else                      { layer = 2; tile = bid - NB0 - NB12; units = 8;  K = K12_; wlds = WLDS12; Wsrc = Wc2; }
  const int nrows = units * 4;
  const int j0 = tile * units;
  _Float16* lwA = lw + (size_t)wlds * nrows * 32;   // A-ring after resident W

  unsigned xcc;
  asm volatile("s_getreg_b32 %0, hwreg(HW_REG_XCC_ID)" : "=s"(xcc));
  xcc &= 7;

  // one-time: stage resident W chunks into LDS, chunk-major + XOR-swizzled quarters
  {
    const int total = wlds * nrows * 4;
    for (int idx = threadIdx.x; idx < total; idx += 640) {
      int c = idx / (nrows * 4);
      int rem = idx % (nrows * 4);
      int r = rem >> 2;
      int q = rem & 3;
      int grow = (r / units) * H_ + j0 + (r % units);
      half8 v = *(const half8*)(Wsrc + (size_t)grow * K + c * 32 + q * 8);
      int qs = q ^ ((r >> 1) & 3);
      *(half8*)(lw + ((size_t)(c * nrows + r) * 32 + qs * 8)) = v;
    }
  }
  __syncthreads();

  const int lane = threadIdx.x & 63;
  const int wv = threadIdx.x >> 6;      // 10 waves
  const int lr = lane & 15;
  const int quad = lane >> 4;
  const int m0 = wv * 32;
  const int m1 = wv * 32 + 16;
  const int j = j0 + ((units == 16) ? lr : (lr & 7));

  // layers 1/2: W chunks 39..47 (own-h tail) live in registers, loaded once.
  // Per-lane fragment = Wsrc[grow(nt*16+lr)][c*32 + quad*8 .. +7] — exactly the
  // value the swizzled LDS read would deliver (read-swizzle cancels store-swizzle).
  half8 wreg[18];
  if (layer != 0) {
#pragma unroll
    for (int cc = 0; cc < NWR12; ++cc)
#pragma unroll
      for (int nt = 0; nt < 2; ++nt) {
        int r = nt * 16 + lr;
        int grow = (r >> 3) * H_ + j0 + (r & 7);   // units = 8
        wreg[cc * 2 + nt] =
            *(const half8*)(Wsrc + (size_t)grow * K + (WLDS12 + cc) * 32 + quad * 8);
      }
  }

  const float bI = bias[layer * G4_ + 0 * H_ + j];
  const float bF = bias[layer * G4_ + 1 * H_ + j];
  const float bG = bias[layer * G4_ + 2 * H_ + j];
  const float bO = bias[layer * G4_ + 3 * H_ + j];

  float cst[2][4] = {{0.f, 0.f, 0.f, 0.f}, {0.f, 0.f, 0.f, 0.f}};

  for (int t = 0; t < T_; ++t) {
    const int s = layer + t;
    const int pprev = (s - 1) & (NP_ - 1);
    const int pcur = s & (NP_ - 1);
    const _Float16* hown = hbuf + (size_t)(layer * NP_ + pprev) * B_ * H_;
    _Float16* hout = hbuf + (size_t)(layer * NP_ + pcur) * B_ * H_;

    // ---- epoch gate: ONE L2 invalidate per XCD per epoch (leader election).
    // Stale parity lines in this XCD's L2 date from epoch s-4 readers; leader
    // fences of epochs s-3..s-1 removed them (skew < 4 enforced by the s-3
    // anti-dep + s-1 own-h waits). CU-private L1 staleness: sc0 on h loads.
    if (threadIdx.x == 0) {
      if (__hip_atomic_fetch_add(&tick[xcc * 128 + s], 1, __ATOMIC_RELAXED,
                                 __HIP_MEMORY_SCOPE_AGENT) == 0) {
        __builtin_amdgcn_fence(__ATOMIC_ACQUIRE, "agent");   // inv L1+L2
        __hip_atomic_store(&leadDone[xcc * 128 + s], 1, __ATOMIC_RELEASE,
                           __HIP_MEMORY_SCOPE_AGENT);
      }
    }
    if (lane == 0) {
      int spin = 0;
      while (__hip_atomic_load(&leadDone[xcc * 128 + s], __ATOMIC_RELAXED,
                               __HIP_MEMORY_SCOPE_AGENT) == 0) {
        __builtin_amdgcn_s_sleep(1);
        if (++spin > 2000000) break;
      }
    }

    floatx4 acc0[2][4];
    floatx4 acc2[2][2];

    if (layer == 0) {
      // merged ring: chunks 0-1 = x0 (constant, cacheable), 2-25 = own-h (sc0).
      // own-layer flag wait fires inside, before chunk 2's DMA.
#pragma unroll
      for (int a = 0; a < 2; ++a)
#pragma unroll
        for (int b = 0; b < 4; ++b) acc0[a][b] = (floatx4){0.f, 0.f, 0.f, 0.f};
      gemm_merged<4, 2, 26, 2, 0, 1, 0>(lw, lwA,
          (const char*)(x0 + (size_t)t * XP_), T_ * XP_,
          (const char*)hown, H_, m0, lane, acc0, flags, s - 1, 0, wreg);
    } else {
      // producer (l-1, s-1) wait, then merged ring at DEPTH 4: chunks 0-23 =
      // h_{l-1} (Wih half, sc0), 24-47 = own-h (Whh half, sc0; 39-47 W from
      // registers); own wait inside at c=24.
      wait_group(flags, s - 1, layer - 1, lane);
#pragma unroll
      for (int a = 0; a < 2; ++a)
#pragma unroll
        for (int b = 0; b < 2; ++b) acc2[a][b] = (floatx4){0.f, 0.f, 0.f, 0.f};
      const char* xsrc = (const char*)(hbuf + (size_t)((layer - 1) * NP_ + pprev) * B_ * H_);
      gemm_merged<2, 4, 48, 24, 1, 1, NWR12>(lw, lwA,
          xsrc, H_, (const char*)hown, H_, m0, lane, acc2, flags, s - 1, layer, wreg);
    }

    // anti-dep (4-parity): (l+1) readers of parity (s&3) ran at their step s-3.
    wait_group(flags, s - 3, layer + 1, lane);

    if (layer == 0) {
#pragma unroll
      for (int mt = 0; mt < 2; ++mt)
#pragma unroll
        for (int r = 0; r < 4; ++r) {
          float iv = acc0[mt][0][r] + bI;
          float fv = acc0[mt][1][r] + bF;
          float gv = acc0[mt][2][r] + bG;
          float ov = acc0[mt][3][r] + bO;
          float cn = sigm(fv) * cst[mt][r] + sigm(iv) * tanh_f(gv);
          cst[mt][r] = cn;
          int m = (mt ? m1 : m0) + quad * 4 + r;
          hout[(size_t)m * H_ + j] = (_Float16)(sigm(ov) * tanh_f(cn));
        }
    } else {
      // tile0 cols: i,f (units 0..7); tile1: g,o. xor-8 colocates the 4 gates.
#pragma unroll
      for (int mt = 0; mt < 2; ++mt)
#pragma unroll
        for (int r = 0; r < 4; ++r) {
          float t0 = acc2[mt][0][r], t1 = acc2[mt][1][r];
          float p0 = __shfl_xor(t0, 8, 64);
          float p1 = __shfl_xor(t1, 8, 64);
          bool lo = (lr < 8);
          float iv = (lo ? t0 : p0) + bI;
          float fv = (lo ? p0 : t0) + bF;
          float gv = (lo ? t1 : p1) + bG;
          float ov = (lo ? p1 : t1) + bO;
          float cn = sigm(fv) * cst[mt][r] + sigm(iv) * tanh_f(gv);
          cst[mt][r] = cn;
          if (lo) {
            int m = (mt ? m1 : m0) + quad * 4 + r;
            hout[(size_t)m * H_ + j] = (_Float16)(sigm(ov) * tanh_f(cn));
          }
        }
    }

    __syncthreads();   // drains vmcnt (all waves' stores) before release
    if (threadIdx.x == 0)
      __hip_atomic_store(&flags[(s * 3 + layer) * 96 + tile], 1, __ATOMIC_RELEASE,
                         __HIP_MEMORY_SCOPE_AGENT);
  }
}

// ---------------- projection + normalize ----------------
__global__ void dvec_kernel(const _Float16* __restrict__ hlast, const float* __restrict__ Wproj,
                            const float* __restrict__ bproj, float* __restrict__ d3) {
  const int m = blockIdx.x;
  const int d = threadIdx.x;
  const _Float16* h = hlast + (size_t)m * H_;
  const float* w = Wproj + (size_t)d * H_;
  float acc = bproj[d];
  for (int k = 0; k < H_; k++) acc += (float)h[k] * w[k];
  __shared__ float red[256];
  red[d] = acc * acc;
  __syncthreads();
  for (int off = 128; off > 0; off >>= 1) {
    if (d < off) red[d] += red[d + off];
    __syncthreads();
  }
  float nrm = sqrtf(red[0]);
  d3[(size_t)m * D_ + d] = acc / nrm;
}

// ---------------- GE2E ----------------
__device__ float block_reduce_sum(float x, float* red) {
  const int d = threadIdx.x;
  red[d] = x;
  __syncthreads();
  for (int off = 128; off > 0; off >>= 1) {
    if (d < off) red[d] += red[d + off];
    __syncthreads();
  }
  float r = red[0];
  __syncthreads();
  return r;
}

__global__ void cent_kernel(const float* __restrict__ d3, float* __restrict__ cent,
                            float* __restrict__ ncent) {
  const int sIdx = blockIdx.x;
  const int d = threadIdx.x;
  float acc = 0.f;
  for (int u = 0; u < U_; u++) acc += d3[((size_t)sIdx * U_ + u) * D_ + d];
  acc *= (1.f / U_);
  cent[sIdx * D_ + d] = acc;
  __shared__ float red[256];
  float n2 = block_reduce_sum(acc * acc, red);
  if (d == 0) ncent[sIdx] = fmaxf(sqrtf(n2), 1e-8f);
}

__global__ void ge2e_kernel(const float* __restrict__ d3, const float* __restrict__ cent,
                            const float* __restrict__ ncent, const float* __restrict__ loss_w,
                            const float* __restrict__ loss_b, float* __restrict__ accums) {
  const int p = blockIdx.x;
  const int sIdx = p / U_;
  const int d = threadIdx.x;
  __shared__ float red[256];
  __shared__ float sims[S_];

  const float v = d3[(size_t)p * D_ + d];
  const float cs = cent[sIdx * D_ + d];
  const float pc = (cs * U_ - v) * (1.f / (U_ - 1));

  float nv2 = block_reduce_sum(v * v, red);
  float npc2 = block_reduce_sum(pc * pc, red);
  float dotp = block_reduce_sum(v * pc, red);

  const float w = loss_w[0], b = loss_b[0];
  const float na = fmaxf(sqrtf(nv2), 1e-6f);
  const float npc = fmaxf(sqrtf(npc2), 1e-6f);
  const float pos_sim = w * (dotp / (na * npc)) + b;
  const float nd = fmaxf(sqrtf(nv2), 1e-8f);

  for (int k = 0; k < S_; k++) {
    float dk = block_reduce_sum(v * cent[k * D_ + d], red);
    if (d == 0) sims[k] = w * (dk / (nd * ncent[k])) + b;
  }
  __syncthreads();
  if (d == 0) {
    float mx = -1e30f;
    for (int k = 0; k < S_; k++)
      if (k != sIdx) mx = fmaxf(mx, sims[k]);
    float se = 0.f, sn = 0.f;
    for (int k = 0; k < S_; k++)
      if (k != sIdx) { se += expf(sims[k] - mx); sn += sims[k]; }
    float lse = mx + logf(se);
    atomicAdd(&accums[0], -pos_sim + lse);
    atomicAdd(&accums[1], pos_sim);
    atomicAdd(&accums[2], sn);
  }
}

__global__ void finalize_kernel(const float* __restrict__ accums, float* __restrict__ out) {
  if (threadIdx.x == 0) {
    out[0] = accums[0] / (float)(S_ * U_);
    out[1] = accums[1] / (float)(S_ * U_);
    out[2] = accums[2] / (float)(S_ * U_ * (S_ - 1));
  }
}

// ---------------- launch ----------------
extern "C" void kernel_launch(void* const* d_in, const int* in_sizes, int n_in,
                              void* d_out, int out_size, void* d_ws, size_t ws_size,
                              hipStream_t stream) {
  const float* mel = (const float*)d_in[0];
  const float* Wih[3] = {(const float*)d_in[1], (const float*)d_in[5], (const float*)d_in[9]};
  const float* Whh[3] = {(const float*)d_in[2], (const float*)d_in[6], (const float*)d_in[10]};
  const float* bih[3] = {(const float*)d_in[3], (const float*)d_in[7], (const float*)d_in[11]};
  const float* bhh[3] = {(const float*)d_in[4], (const float*)d_in[8], (const float*)d_in[12]};
  const float* Wproj = (const float*)d_in[13];
  const float* bproj = (const float*)d_in[14];
  const float* loss_w = (const float*)d_in[15];
  const float* loss_b = (const float*)d_in[16];
  float* out = (float*)d_out;

  char* ws = (char*)d_ws;
  size_t off = 0;
  auto alloc = [&](size_t bytes) -> void* {
    void* p = ws + off;
    off = (off + bytes + 255) & ~(size_t)255;
    return p;
  };
  _Float16* x0   = (_Float16*)alloc((size_t)B_ * T_ * XP_ * 2);
  _Float16* Wc0  = (_Float16*)alloc((size_t)G4_ * K0_ * 2);
  _Float16* Wc1  = (_Float16*)alloc((size_t)G4_ * K12_ * 2);
  _Float16* Wc2  = (_Float16*)alloc((size_t)G4_ * K12_ * 2);
  float*    bias = (float*)alloc((size_t)3 * G4_ * 4);
  _Float16* hbuf = (_Float16*)alloc((size_t)3 * NP_ * B_ * H_ * 2);
  float*    d3   = (float*)alloc((size_t)B_ * D_ * 4);
  float*    cent = (float*)alloc((size_t)S_ * D_ * 4);
  float*    ncent = (float*)alloc((size_t)S_ * 4);
  float*    accums = (float*)alloc(64);
  int*      flags = (int*)alloc((size_t)(T_ + 3) * 3 * 96 * 4);
  int*      tick  = (int*)alloc((size_t)8 * 128 * 4);
  int*      lead  = (int*)alloc((size_t)8 * 128 * 4);

  hipMemsetAsync(hbuf, 0, (size_t)3 * NP_ * B_ * H_ * 2, stream);
  hipMemsetAsync(accums, 0, 64, stream);
  hipMemsetAsync(flags, 0, (size_t)(T_ + 3) * 3 * 96 * 4, stream);
  hipMemsetAsync(tick, 0, (size_t)8 * 128 * 4, stream);
  hipMemsetAsync(lead, 0, (size_t)8 * 128 * 4, stream);

  prep_x0<<<(B_ * T_ * XP_ + 255) / 256, 256, 0, stream>>>(mel, x0);
  prep_w0<<<(G4_ * K0_ + 255) / 256, 256, 0, stream>>>(Wih[0], Whh[0], Wc0);
  prep_w12<<<(G4_ * K12_ + 255) / 256, 256, 0, stream>>>(Wih[1], Whh[1], Wc1);
  prep_w12<<<(G4_ * K12_ + 255) / 256, 256, 0, stream>>>(Wih[2], Whh[2], Wc2);
  for (int l = 0; l < 3; l++)
    prep_bias<<<(G4_ + 255) / 256, 256, 0, stream>>>(bih[l], bhh[l], bias + l * G4_);

  hipFuncSetAttribute((const void*)lstm_persist,
                      hipFuncAttributeMaxDynamicSharedMemorySize, SMEM_BYTES);
  void* kargs[] = {(void*)&x0, (void*)&Wc0, (void*)&Wc1, (void*)&Wc2,
                   (void*)&bias, (void*)&hbuf, (void*)&flags, (void*)&tick,
                   (void*)&lead};
  hipLaunchCooperativeKernel((const void*)lstm_persist, dim3(NBLK), dim3(640),
                             kargs, SMEM_BYTES, stream);

  // layer-2 final h: s = 2 + 119 = 121 -> parity 121 & 3 = 1
  const _Float16* hlast = hbuf + (size_t)(2 * NP_ + 1) * B_ * H_;
  dvec_kernel<<<B_, 256, 0, stream>>>(hlast, Wproj, bproj, d3);
  cent_kernel<<<S_, 256, 0, stream>>>(d3, cent, ncent);
  ge2e_kernel<<<B_, 256, 0, stream>>>(d3, cent, ncent, loss_w, loss_b, accums);
  finalize_kernel<<<1, 64, 0, stream>>>(accums, out);
}